// Round 5
// baseline (99.160 us; speedup 1.0000x reference)
//
#include <hip/hip_runtime.h>

#define NROWS 32768
#define NE    1024
#define ED    64
#define CHUNK 128              // codes staged per LDS chunk
#define NCH   (NE / CHUNK)     // 8 chunks
#define SLICE (CHUNK / 4)      // 32 codes per wave per chunk

typedef float4 f4;

// ---------------------------------------------------------------------------
// Prep: per-code ||e||^2 with numpy pairwise-8 op order (exact f32 replication)
// ---------------------------------------------------------------------------
__global__ void vq_prep(const float* __restrict__ cb, float* __restrict__ ssq)
{
    int j = blockIdx.x * blockDim.x + threadIdx.x;   // 0..1023
    const f4* crow = (const f4*)(cb + (size_t)j * ED);
    float v[ED];
#pragma unroll
    for (int i = 0; i < 16; ++i) {
        f4 t = crow[i];
        v[4*i+0] = t.x; v[4*i+1] = t.y; v[4*i+2] = t.z; v[4*i+3] = t.w;
    }
    {
#pragma clang fp contract(off)
        float r0 = v[0]*v[0], r1 = v[1]*v[1], r2 = v[2]*v[2], r3 = v[3]*v[3];
        float r4 = v[4]*v[4], r5 = v[5]*v[5], r6 = v[6]*v[6], r7 = v[7]*v[7];
#pragma unroll
        for (int i = 8; i < ED; i += 8) {
            r0 += v[i+0]*v[i+0]; r1 += v[i+1]*v[i+1];
            r2 += v[i+2]*v[i+2]; r3 += v[i+3]*v[i+3];
            r4 += v[i+4]*v[i+4]; r5 += v[i+5]*v[i+5];
            r6 += v[i+6]*v[i+6]; r7 += v[i+7]*v[i+7];
        }
        ssq[j] = ((r0+r1)+(r2+r3)) + ((r4+r5)+(r6+r7));
    }
}

// ---------------------------------------------------------------------------
// Main: lane = z-row (64 rows/block pinned in VGPRs via asm), 4 waves split
// each 128-code LDS chunk into 32-code slices. Codebook read as wave-uniform
// ds_read_b128 broadcast -> v_fmac with VGPR z operand: no SMEM latency, no
// per-lane VMEM, near-zero argmin overhead (per-lane sequential scan).
// Numerics identical to passing round 3:
//   cn/ssq numpy pairwise-8; dot ascending-k single-acc fmaf;
//   d = fl(fl(cn+ssq_j) - 2*dot); first-index argmin (strict < per wave,
//   lex (d,idx) across waves).
// ---------------------------------------------------------------------------
__global__ __launch_bounds__(256, 4)
void vq_main(const float* __restrict__ z, const float* __restrict__ cb,
             const float* __restrict__ ssq, float* __restrict__ out,
             float* __restrict__ partials)
{
    __shared__ __align__(16) float et[CHUNK * ED];   // 32 KB
    __shared__ __align__(16) float sqsh[NE];         // 4 KB
    __shared__ float cv[4][64];
    __shared__ int   ci[4][64];
    __shared__ int   idxsh[64];
    __shared__ float wsum[4];

    const int tid  = threadIdx.x;
    const int lane = tid & 63;
    const int w    = tid >> 6;               // wave 0..3
    const int row  = blockIdx.x * 64 + lane; // this lane's z-row (all waves alias)

    // stage all 1024 ssq (visible after first chunk barrier)
    ((f4*)sqsh)[tid] = ((const f4*)ssq)[tid];

    // ---- own row -> 16 f4 VGPRs, pinned against rematerialization ----
    f4 zr[16];
    {
        const f4* zrow = (const f4*)(z + (size_t)row * ED);
#pragma unroll
        for (int q = 0; q < 16; ++q) zr[q] = zrow[q];
#pragma unroll
        for (int q = 0; q < 16; ++q)
            asm volatile("" : "+v"(zr[q].x), "+v"(zr[q].y),
                              "+v"(zr[q].z), "+v"(zr[q].w));
    }

    // ---- row norm, numpy pairwise-8 (k = 4q+c; accumulator = k mod 8) ----
    float cn;
    {
#pragma clang fp contract(off)
        float r0 = zr[0].x*zr[0].x, r1 = zr[0].y*zr[0].y;
        float r2 = zr[0].z*zr[0].z, r3 = zr[0].w*zr[0].w;
        float r4 = zr[1].x*zr[1].x, r5 = zr[1].y*zr[1].y;
        float r6 = zr[1].z*zr[1].z, r7 = zr[1].w*zr[1].w;
#pragma unroll
        for (int q = 2; q < 16; q += 2) {
            r0 += zr[q].x*zr[q].x;     r1 += zr[q].y*zr[q].y;
            r2 += zr[q].z*zr[q].z;     r3 += zr[q].w*zr[q].w;
            r4 += zr[q+1].x*zr[q+1].x; r5 += zr[q+1].y*zr[q+1].y;
            r6 += zr[q+1].z*zr[q+1].z; r7 += zr[q+1].w*zr[q+1].w;
        }
        cn = ((r0+r1)+(r2+r3)) + ((r4+r5)+(r6+r7));
    }

    // ---- scan all 1024 codes in 8 staged chunks ----
    float bv = INFINITY;
    int   bi = 0;

    for (int ch = 0; ch < NCH; ++ch) {
        __syncthreads();   // previous chunk's readers done (also fences sqsh)
        {
            // coalesced flat copy: 128 codes x 64 f32 = 2048 f4; 8 f4/thread
            const f4* src = (const f4*)cb + (size_t)ch * (CHUNK * 16) + tid;
            f4* dst = (f4*)et + tid;
#pragma unroll
            for (int i = 0; i < 8; ++i) dst[i * 256] = src[i * 256];
        }
        __syncthreads();

        const int jb = ch * CHUNK + w * SLICE;        // global code base
        const float* ebase = et + (size_t)(w * SLICE) * ED;

#pragma unroll 2
        for (int jj = 0; jj < SLICE; jj += 2) {
            const f4* e0 = (const f4*)(ebase + (size_t)jj * ED);
            const f4* e1 = e0 + 16;
            float a0 = 0.f, a1 = 0.f;
#pragma unroll
            for (int q = 0; q < 16; ++q) {
                f4 u = e0[q];          // uniform -> LDS broadcast
                f4 t = e1[q];
                a0 = fmaf(u.x, zr[q].x, a0);
                a0 = fmaf(u.y, zr[q].y, a0);
                a0 = fmaf(u.z, zr[q].z, a0);
                a0 = fmaf(u.w, zr[q].w, a0);
                a1 = fmaf(t.x, zr[q].x, a1);
                a1 = fmaf(t.y, zr[q].y, a1);
                a1 = fmaf(t.z, zr[q].z, a1);
                a1 = fmaf(t.w, zr[q].w, a1);
            }
            {
#pragma clang fp contract(off)
                float t0 = cn + sqsh[jb + jj];
                float t1 = cn + sqsh[jb + jj + 1];
                float d0 = t0 - 2.0f * a0;            // 2*a exact
                float d1 = t1 - 2.0f * a1;
                if (d0 < bv) { bv = d0; bi = jb + jj; }
                if (d1 < bv) { bv = d1; bi = jb + jj + 1; }
            }
        }
    }

    cv[w][lane] = bv;
    ci[w][lane] = bi;
    __syncthreads();

    // ---- combine 4 wave-candidates per row: lex (d, idx) -> first index ----
    if (tid < 64) {
        float v = cv[0][tid]; int i = ci[0][tid];
#pragma unroll
        for (int u = 1; u < 4; ++u) {
            float vu = cv[u][tid]; int iu = ci[u][tid];
            if (vu < v || (vu == v && iu < i)) { v = vu; i = iu; }
        }
        i &= (NE - 1);                        // defensive no-op
        idxsh[tid] = i;
        out[(size_t)NROWS * ED + blockIdx.x * 64 + tid] = (float)i;
    }
    __syncthreads();

    // ---- epilogue: row = lane, dims [w*16, w*16+16) from pinned zr ----
    const int ii = idxsh[lane];
    const f4* eq = (const f4*)(cb + (size_t)ii * ED) + w * 4;
    f4 e0 = eq[0], e1 = eq[1], e2 = eq[2], e3 = eq[3];
    f4 z0, z1, z2, z3;
    switch (w) {                               // compile-time zr indices
        case 0:  z0 = zr[0];  z1 = zr[1];  z2 = zr[2];  z3 = zr[3];  break;
        case 1:  z0 = zr[4];  z1 = zr[5];  z2 = zr[6];  z3 = zr[7];  break;
        case 2:  z0 = zr[8];  z1 = zr[9];  z2 = zr[10]; z3 = zr[11]; break;
        default: z0 = zr[12]; z1 = zr[13]; z2 = zr[14]; z3 = zr[15]; break;
    }
    float lp = 0.f;
    f4 o0, o1, o2, o3;
    {
#pragma clang fp contract(off)
        float d;
        d = e0.x - z0.x; o0.x = z0.x + d; lp += d*d;
        d = e0.y - z0.y; o0.y = z0.y + d; lp += d*d;
        d = e0.z - z0.z; o0.z = z0.z + d; lp += d*d;
        d = e0.w - z0.w; o0.w = z0.w + d; lp += d*d;
        d = e1.x - z1.x; o1.x = z1.x + d; lp += d*d;
        d = e1.y - z1.y; o1.y = z1.y + d; lp += d*d;
        d = e1.z - z1.z; o1.z = z1.z + d; lp += d*d;
        d = e1.w - z1.w; o1.w = z1.w + d; lp += d*d;
        d = e2.x - z2.x; o2.x = z2.x + d; lp += d*d;
        d = e2.y - z2.y; o2.y = z2.y + d; lp += d*d;
        d = e2.z - z2.z; o2.z = z2.z + d; lp += d*d;
        d = e2.w - z2.w; o2.w = z2.w + d; lp += d*d;
        d = e3.x - z3.x; o3.x = z3.x + d; lp += d*d;
        d = e3.y - z3.y; o3.y = z3.y + d; lp += d*d;
        d = e3.z - z3.z; o3.z = z3.z + d; lp += d*d;
        d = e3.w - z3.w; o3.w = z3.w + d; lp += d*d;
    }
    f4* og = (f4*)(out + (size_t)row * ED) + w * 4;
    og[0] = o0; og[1] = o1; og[2] = o2; og[3] = o3;

    // ---- deterministic loss partial ----
#pragma unroll
    for (int m = 1; m < 64; m <<= 1) lp += __shfl_xor(lp, m);
    if (lane == 0) wsum[w] = lp;
    __syncthreads();
    if (tid == 0)
        partials[blockIdx.x] = (wsum[0] + wsum[1]) + (wsum[2] + wsum[3]);
}

// ---------------------------------------------------------------------------
// Finalize: deterministic tree-sum of 512 partials -> loss scalar (f32)
// ---------------------------------------------------------------------------
__global__ void vq_finalize(const float* __restrict__ partials,
                            float* __restrict__ out)
{
    __shared__ float red[256];
    int t = threadIdx.x;
    red[t] = partials[t] + partials[t + 256];
    __syncthreads();
    for (int m = 128; m > 0; m >>= 1) {
        if (t < m) red[t] += red[t + m];
        __syncthreads();
    }
    if (t == 0) {
        float mean = red[0] / (float)((size_t)NROWS * ED);
        out[(size_t)NROWS * ED + NROWS] = mean + 0.25f * mean;  // (1+BETA)*mean
    }
}

extern "C" void kernel_launch(void* const* d_in, const int* in_sizes, int n_in,
                              void* d_out, int out_size, void* d_ws, size_t ws_size,
                              hipStream_t stream)
{
    (void)in_sizes; (void)n_in; (void)out_size; (void)ws_size;
    const float* z  = (const float*)d_in[0];
    const float* cb = (const float*)d_in[1];
    float* out = (float*)d_out;
    float* ssq      = (float*)d_ws;          // 1024 f32
    float* partials = ssq + NE;              // 512 f32

    vq_prep<<<4, 256, 0, stream>>>(cb, ssq);
    vq_main<<<512, 256, 0, stream>>>(z, cb, ssq, out, partials);
    vq_finalize<<<1, 256, 0, stream>>>(partials, out);
}

// Round 6
// 87.800 us; speedup vs baseline: 1.1294x; 1.1294x over previous
//
#include <hip/hip_runtime.h>

#define NROWS 32768
#define NE    1024
#define ED    64
#define CHUNK 256              // codes per LDS chunk
#define NCH   (NE / CHUNK)     // 4 chunks
#define RPW   8                // rows per wave

typedef float4 f4;

// ---------------------------------------------------------------------------
// Prep: per-code ||e||^2 with numpy pairwise-8 op order (exact f32 replication)
// ---------------------------------------------------------------------------
__global__ void vq_prep(const float* __restrict__ cb, float* __restrict__ ssq)
{
    int j = blockIdx.x * blockDim.x + threadIdx.x;   // 0..1023
    const f4* crow = (const f4*)(cb + (size_t)j * ED);
    float v[ED];
#pragma unroll
    for (int i = 0; i < 16; ++i) {
        f4 t = crow[i];
        v[4*i+0] = t.x; v[4*i+1] = t.y; v[4*i+2] = t.z; v[4*i+3] = t.w;
    }
    {
#pragma clang fp contract(off)
        float r0 = v[0]*v[0], r1 = v[1]*v[1], r2 = v[2]*v[2], r3 = v[3]*v[3];
        float r4 = v[4]*v[4], r5 = v[5]*v[5], r6 = v[6]*v[6], r7 = v[7]*v[7];
#pragma unroll
        for (int i = 8; i < ED; i += 8) {
            r0 += v[i+0]*v[i+0]; r1 += v[i+1]*v[i+1];
            r2 += v[i+2]*v[i+2]; r3 += v[i+3]*v[i+3];
            r4 += v[i+4]*v[i+4]; r5 += v[i+5]*v[i+5];
            r6 += v[i+6]*v[i+6]; r7 += v[i+7]*v[i+7];
        }
        ssq[j] = ((r0+r1)+(r2+r3)) + ((r4+r5)+(r6+r7));
    }
}

// ---------------------------------------------------------------------------
// Main (r3 structure + z via scalar loads):
//  - block: 32 rows, 4 waves; each wave evaluates ALL codes for its 8 rows.
//  - codebook chunk (256 codes) transposed in LDS [64 k][256 codes];
//    lane owns the f4 code-column {4*lane..4*lane+3}.
//  - z fragments (row, k4) are wave-uniform -> s_load_dwordx4 (SMEM pipe);
//    inner loop: v_fmac v_acc, s_z, v_e. LDS pipe = e-reads only.
// Numerics identical to the passing round-3 kernel:
//   cn/ssq numpy pairwise-8; dot ascending-k single-acc fmaf;
//   d = fl(fl(cn+ssq_j) - 2*dot); first-index argmin (strict < ascending j,
//   lex (d,idx) across lanes).
// ---------------------------------------------------------------------------
__global__ __launch_bounds__(256, 2)
void vq_main(const float* __restrict__ z, const float* __restrict__ cb,
             const float* __restrict__ ssq, float* __restrict__ out,
             float* __restrict__ partials)
{
    __shared__ __align__(16) float et[ED * CHUNK];   // 64 KB transposed chunk
    __shared__ __align__(16) float sqsh[NE];         // 4 KB
    __shared__ int   idxsh[32];
    __shared__ float wsum[4];

    const int tid  = threadIdx.x;
    const int lane = tid & 63;
    const int w    = tid >> 6;                               // wave 0..3
    const int w_u  = __builtin_amdgcn_readfirstlane(w);      // scalar wave id
    const int rowbase = blockIdx.x * 32;

    // stage all 1024 ssq once (first chunk barrier fences it)
    ((f4*)sqsh)[tid] = ((const f4*)ssq)[tid];

    // ---- row norms for this wave's 8 rows, numpy pairwise-8 ----
    float cn[RPW];
    {
        const int rl = lane >> 3;            // row within wave's 8
        const int jj = lane & 7;             // accumulator index
        const float* zr = z + (size_t)(rowbase + w_u * RPW + rl) * ED;
        float a;
        {
#pragma clang fp contract(off)
            a = 0.f;
#pragma unroll
            for (int i = 0; i < 8; ++i) { float v = zr[8*i + jj]; a += v*v; }
        }
        a += __shfl_xor(a, 1);
        a += __shfl_xor(a, 2);
        a += __shfl_xor(a, 4);
#pragma unroll
        for (int r = 0; r < RPW; ++r) cn[r] = __shfl(a, r * 8);
    }

    float bestv[RPW];
    int   besti[RPW];
#pragma unroll
    for (int r = 0; r < RPW; ++r) { bestv[r] = INFINITY; besti[r] = 0; }

    const f4* et4 = (const f4*)et;                           // [64][64] f4
    const float* zw = z + (size_t)(rowbase + w_u * RPW) * ED; // scalar base

    for (int ch = 0; ch < NCH; ++ch) {
        __syncthreads();   // previous chunk's readers done (also fences sqsh)
        // ---- stage chunk: thread tid stages code ch*256+tid, transposed ----
        {
            const f4* crow = (const f4*)(cb + (size_t)(ch * CHUNK + tid) * ED);
#pragma unroll
            for (int i = 0; i < 16; ++i) {
                f4 t = crow[i];
                et[(4*i+0) * CHUNK + tid] = t.x;
                et[(4*i+1) * CHUNK + tid] = t.y;
                et[(4*i+2) * CHUNK + tid] = t.z;
                et[(4*i+3) * CHUNK + tid] = t.w;
            }
        }
        __syncthreads();

        f4 sv = ((const f4*)sqsh)[ch * 64 + lane];
        float svq[4] = {sv.x, sv.y, sv.z, sv.w};

        float acc[RPW][4];
#pragma unroll
        for (int r = 0; r < RPW; ++r)
            acc[r][0] = acc[r][1] = acc[r][2] = acc[r][3] = 0.f;

#pragma unroll 2
        for (int k4 = 0; k4 < 16; ++k4) {
            // e: per-lane code column, k-dims 4k4..4k4+3 (LDS pipe)
            f4 e0 = et4[(4*k4+0) * 64 + lane];
            f4 e1 = et4[(4*k4+1) * 64 + lane];
            f4 e2 = et4[(4*k4+2) * 64 + lane];
            f4 e3 = et4[(4*k4+3) * 64 + lane];
            // z: wave-uniform fragments -> s_load_dwordx4 (SMEM pipe)
            f4 z0 = *(const f4*)(zw + 0*ED + 4*k4);
            f4 z1 = *(const f4*)(zw + 1*ED + 4*k4);
            f4 z2 = *(const f4*)(zw + 2*ED + 4*k4);
            f4 z3 = *(const f4*)(zw + 3*ED + 4*k4);
            f4 z4 = *(const f4*)(zw + 4*ED + 4*k4);
            f4 z5 = *(const f4*)(zw + 5*ED + 4*k4);
            f4 z6 = *(const f4*)(zw + 6*ED + 4*k4);
            f4 z7 = *(const f4*)(zw + 7*ED + 4*k4);
#define ROWFMA(r, zz)                                                    \
            acc[r][0] = fmaf(zz.x, e0.x, acc[r][0]);                     \
            acc[r][1] = fmaf(zz.x, e0.y, acc[r][1]);                     \
            acc[r][2] = fmaf(zz.x, e0.z, acc[r][2]);                     \
            acc[r][3] = fmaf(zz.x, e0.w, acc[r][3]);                     \
            acc[r][0] = fmaf(zz.y, e1.x, acc[r][0]);                     \
            acc[r][1] = fmaf(zz.y, e1.y, acc[r][1]);                     \
            acc[r][2] = fmaf(zz.y, e1.z, acc[r][2]);                     \
            acc[r][3] = fmaf(zz.y, e1.w, acc[r][3]);                     \
            acc[r][0] = fmaf(zz.z, e2.x, acc[r][0]);                     \
            acc[r][1] = fmaf(zz.z, e2.y, acc[r][1]);                     \
            acc[r][2] = fmaf(zz.z, e2.z, acc[r][2]);                     \
            acc[r][3] = fmaf(zz.z, e2.w, acc[r][3]);                     \
            acc[r][0] = fmaf(zz.w, e3.x, acc[r][0]);                     \
            acc[r][1] = fmaf(zz.w, e3.y, acc[r][1]);                     \
            acc[r][2] = fmaf(zz.w, e3.z, acc[r][2]);                     \
            acc[r][3] = fmaf(zz.w, e3.w, acc[r][3]);
            ROWFMA(0, z0) ROWFMA(1, z1) ROWFMA(2, z2) ROWFMA(3, z3)
            ROWFMA(4, z4) ROWFMA(5, z5) ROWFMA(6, z6) ROWFMA(7, z7)
#undef ROWFMA
        }

        {
#pragma clang fp contract(off)
#pragma unroll
            for (int r = 0; r < RPW; ++r) {
#pragma unroll
                for (int q = 0; q < 4; ++q) {
                    float t1 = cn[r] + svq[q];
                    float d  = t1 - 2.0f * acc[r][q];      // 2*acc exact
                    int j = ch * CHUNK + lane * 4 + q;
                    if (d < bestv[r]) { bestv[r] = d; besti[r] = j; }
                }
            }
        }
    }

    // ---- cross-lane lexicographic (val, idx) argmin + epilogue ----
    float lp = 0.f;
#pragma unroll
    for (int r = 0; r < RPW; ++r) {
        float v = bestv[r];
        int   i = besti[r];
#pragma unroll
        for (int m = 1; m < 64; m <<= 1) {
            float ov = __shfl_xor(v, m);
            int   oi = __shfl_xor(i, m);
            if (ov < v || (ov == v && oi < i)) { v = ov; i = oi; }
        }
        i &= (NE - 1);                       // defensive no-op
        const int grow = rowbase + w * RPW + r;
        float zq, zz, diff, st;
        {
#pragma clang fp contract(off)
            zq   = cb[(size_t)i * ED + lane];
            zz   = z [(size_t)grow * ED + lane];
            diff = zq - zz;                  // (z_q - z)
            st   = zz + diff;                // z + sg(z_q - z)
            lp  += diff * diff;
        }
        out[(size_t)grow * ED + lane] = st;
        if (lane == 0) idxsh[w * RPW + r] = i;
    }

    // ---- deterministic loss partial ----
#pragma unroll
    for (int m = 1; m < 64; m <<= 1) lp += __shfl_xor(lp, m);
    if (lane == 0) wsum[w] = lp;
    __syncthreads();

    // ---- uniform coalesced idx store (f32) ----
    if (tid < 32) {
        int iv = idxsh[tid] & (NE - 1);
        out[(size_t)NROWS * ED + rowbase + tid] = (float)iv;
    }
    if (tid == 0)
        partials[blockIdx.x] = (wsum[0] + wsum[1]) + (wsum[2] + wsum[3]);
}

// ---------------------------------------------------------------------------
// Finalize: deterministic tree-sum of 1024 partials -> loss scalar (f32)
// ---------------------------------------------------------------------------
__global__ void vq_finalize(const float* __restrict__ partials,
                            float* __restrict__ out)
{
    __shared__ float red[256];
    int t = threadIdx.x;
    float s = (partials[t] + partials[t + 256]) + (partials[t + 512] + partials[t + 768]);
    red[t] = s;
    __syncthreads();
    for (int m = 128; m > 0; m >>= 1) {
        if (t < m) red[t] += red[t + m];
        __syncthreads();
    }
    if (t == 0) {
        float mean = red[0] / (float)((size_t)NROWS * ED);
        out[(size_t)NROWS * ED + NROWS] = mean + 0.25f * mean;  // (1+BETA)*mean
    }
}

extern "C" void kernel_launch(void* const* d_in, const int* in_sizes, int n_in,
                              void* d_out, int out_size, void* d_ws, size_t ws_size,
                              hipStream_t stream)
{
    (void)in_sizes; (void)n_in; (void)out_size; (void)ws_size;
    const float* z  = (const float*)d_in[0];
    const float* cb = (const float*)d_in[1];
    float* out = (float*)d_out;
    float* ssq      = (float*)d_ws;          // 1024 f32
    float* partials = ssq + NE;              // 1024 f32

    vq_prep<<<4, 256, 0, stream>>>(cb, ssq);
    vq_main<<<1024, 256, 0, stream>>>(z, cb, ssq, out, partials);
    vq_finalize<<<1, 256, 0, stream>>>(partials, out);
}

// Round 7
// 74.381 us; speedup vs baseline: 1.3331x; 1.1804x over previous
//
#include <hip/hip_runtime.h>

#define NROWS 32768
#define NE    1024
#define ED    64
#define CHUNK 128              // codes per LDS chunk (32 KB transposed)
#define NCH   (NE / CHUNK)     // 8 chunks
#define RPW   8                // rows per wave

typedef float4 f4;
typedef float2 f2;

// ---------------------------------------------------------------------------
// Prep: per-code ||e||^2 with numpy pairwise-8 op order (exact f32 replication)
// ---------------------------------------------------------------------------
__global__ void vq_prep(const float* __restrict__ cb, float* __restrict__ ssq)
{
    int j = blockIdx.x * blockDim.x + threadIdx.x;   // 0..1023
    const f4* crow = (const f4*)(cb + (size_t)j * ED);
    float v[ED];
#pragma unroll
    for (int i = 0; i < 16; ++i) {
        f4 t = crow[i];
        v[4*i+0] = t.x; v[4*i+1] = t.y; v[4*i+2] = t.z; v[4*i+3] = t.w;
    }
    {
#pragma clang fp contract(off)
        float r0 = v[0]*v[0], r1 = v[1]*v[1], r2 = v[2]*v[2], r3 = v[3]*v[3];
        float r4 = v[4]*v[4], r5 = v[5]*v[5], r6 = v[6]*v[6], r7 = v[7]*v[7];
#pragma unroll
        for (int i = 8; i < ED; i += 8) {
            r0 += v[i+0]*v[i+0]; r1 += v[i+1]*v[i+1];
            r2 += v[i+2]*v[i+2]; r3 += v[i+3]*v[i+3];
            r4 += v[i+4]*v[i+4]; r5 += v[i+5]*v[i+5];
            r6 += v[i+6]*v[i+6]; r7 += v[i+7]*v[i+7];
        }
        ssq[j] = ((r0+r1)+(r2+r3)) + ((r4+r5)+(r6+r7));
    }
}

// ---------------------------------------------------------------------------
// Main (r6 structure, CHUNK halved for 4 blocks/CU occupancy):
//  - block: 32 rows, 4 waves; each wave evaluates ALL codes for its 8 rows.
//  - codebook chunk (128 codes) transposed in LDS [64 dim][128 code];
//    lane owns code pair {2*lane, 2*lane+1} (float2 reads, 2-way = free).
//  - z fragments (row, k4) wave-uniform -> s_load_dwordx4 (SMEM pipe);
//    inner loop: v_fmac v_acc, s_z, v_e. LDS pipe = e-reads only.
// Numerics identical to passing rounds 3/6:
//   cn/ssq numpy pairwise-8; dot ascending-k single-acc fmaf;
//   d = fl(fl(cn+ssq_j) - 2*dot); first-index argmin (strict < ascending j,
//   lex (d,idx) across lanes).
// ---------------------------------------------------------------------------
__global__ __launch_bounds__(256, 4)
void vq_main(const float* __restrict__ z, const float* __restrict__ cb,
             const float* __restrict__ ssq, float* __restrict__ out,
             float* __restrict__ partials)
{
    __shared__ __align__(16) float et[ED * CHUNK];   // 32 KB transposed chunk
    __shared__ __align__(16) float sqsh[NE];         // 4 KB
    __shared__ int   idxsh[32];
    __shared__ float wsum[4];

    const int tid  = threadIdx.x;
    const int lane = tid & 63;
    const int w    = tid >> 6;                               // wave 0..3
    const int w_u  = __builtin_amdgcn_readfirstlane(w);      // scalar wave id
    const int rowbase = blockIdx.x * 32;

    // stage all 1024 ssq once (first chunk barrier fences it)
    ((f4*)sqsh)[tid] = ((const f4*)ssq)[tid];

    // ---- row norms for this wave's 8 rows, numpy pairwise-8 ----
    float cn[RPW];
    {
        const int rl = lane >> 3;            // row within wave's 8
        const int jj = lane & 7;             // accumulator index
        const float* zr = z + (size_t)(rowbase + w_u * RPW + rl) * ED;
        float a;
        {
#pragma clang fp contract(off)
            a = 0.f;
#pragma unroll
            for (int i = 0; i < 8; ++i) { float v = zr[8*i + jj]; a += v*v; }
        }
        a += __shfl_xor(a, 1);
        a += __shfl_xor(a, 2);
        a += __shfl_xor(a, 4);
#pragma unroll
        for (int r = 0; r < RPW; ++r) cn[r] = __shfl(a, r * 8);
    }

    float bestv[RPW];
    int   besti[RPW];
#pragma unroll
    for (int r = 0; r < RPW; ++r) { bestv[r] = INFINITY; besti[r] = 0; }

    const f2* et2 = (const f2*)et;                            // [64][64] f2
    const float* zw = z + (size_t)(rowbase + w_u * RPW) * ED; // scalar base

    for (int ch = 0; ch < NCH; ++ch) {
        __syncthreads();   // previous chunk's readers done (also fences sqsh)
        // ---- stage chunk transposed: 2 threads per code (32 dims each) ----
        {
            const int c = tid & 127;          // code within chunk
            const int h = tid >> 7;           // dim half
            const f4* crow = (const f4*)(cb + (size_t)(ch * CHUNK + c) * ED
                                         + h * 32);
#pragma unroll
            for (int i = 0; i < 8; ++i) {
                f4 t = crow[i];
                const int dim = h * 32 + 4 * i;
                et[(dim+0) * CHUNK + c] = t.x;
                et[(dim+1) * CHUNK + c] = t.y;
                et[(dim+2) * CHUNK + c] = t.z;
                et[(dim+3) * CHUNK + c] = t.w;
            }
        }
        __syncthreads();

        f2 sv = ((const f2*)sqsh)[ch * 64 + lane];
        float svq[2] = {sv.x, sv.y};

        float acc[RPW][2];
#pragma unroll
        for (int r = 0; r < RPW; ++r) acc[r][0] = acc[r][1] = 0.f;

#pragma unroll 2
        for (int k4 = 0; k4 < 16; ++k4) {
            // e: lane's code pair at dims 4k4..4k4+3 (LDS pipe, 2-way free)
            f2 e0 = et2[(4*k4+0) * 64 + lane];
            f2 e1 = et2[(4*k4+1) * 64 + lane];
            f2 e2 = et2[(4*k4+2) * 64 + lane];
            f2 e3 = et2[(4*k4+3) * 64 + lane];
            // z: wave-uniform fragments -> s_load_dwordx4 (SMEM pipe)
            f4 z0 = *(const f4*)(zw + 0*ED + 4*k4);
            f4 z1 = *(const f4*)(zw + 1*ED + 4*k4);
            f4 z2 = *(const f4*)(zw + 2*ED + 4*k4);
            f4 z3 = *(const f4*)(zw + 3*ED + 4*k4);
            f4 z4 = *(const f4*)(zw + 4*ED + 4*k4);
            f4 z5 = *(const f4*)(zw + 5*ED + 4*k4);
            f4 z6 = *(const f4*)(zw + 6*ED + 4*k4);
            f4 z7 = *(const f4*)(zw + 7*ED + 4*k4);
#define ROWFMA(r, zz)                                                    \
            acc[r][0] = fmaf(zz.x, e0.x, acc[r][0]);                     \
            acc[r][1] = fmaf(zz.x, e0.y, acc[r][1]);                     \
            acc[r][0] = fmaf(zz.y, e1.x, acc[r][0]);                     \
            acc[r][1] = fmaf(zz.y, e1.y, acc[r][1]);                     \
            acc[r][0] = fmaf(zz.z, e2.x, acc[r][0]);                     \
            acc[r][1] = fmaf(zz.z, e2.y, acc[r][1]);                     \
            acc[r][0] = fmaf(zz.w, e3.x, acc[r][0]);                     \
            acc[r][1] = fmaf(zz.w, e3.y, acc[r][1]);
            ROWFMA(0, z0) ROWFMA(1, z1) ROWFMA(2, z2) ROWFMA(3, z3)
            ROWFMA(4, z4) ROWFMA(5, z5) ROWFMA(6, z6) ROWFMA(7, z7)
#undef ROWFMA
        }

        {
#pragma clang fp contract(off)
#pragma unroll
            for (int r = 0; r < RPW; ++r) {
#pragma unroll
                for (int q = 0; q < 2; ++q) {
                    float t1 = cn[r] + svq[q];
                    float d  = t1 - 2.0f * acc[r][q];      // 2*acc exact
                    int j = ch * CHUNK + lane * 2 + q;
                    if (d < bestv[r]) { bestv[r] = d; besti[r] = j; }
                }
            }
        }
    }

    // ---- cross-lane lexicographic (val, idx) argmin + epilogue ----
    float lp = 0.f;
#pragma unroll
    for (int r = 0; r < RPW; ++r) {
        float v = bestv[r];
        int   i = besti[r];
#pragma unroll
        for (int m = 1; m < 64; m <<= 1) {
            float ov = __shfl_xor(v, m);
            int   oi = __shfl_xor(i, m);
            if (ov < v || (ov == v && oi < i)) { v = ov; i = oi; }
        }
        i &= (NE - 1);                       // defensive no-op
        const int grow = rowbase + w * RPW + r;
        float zq, zz, diff, st;
        {
#pragma clang fp contract(off)
            zq   = cb[(size_t)i * ED + lane];
            zz   = z [(size_t)grow * ED + lane];
            diff = zq - zz;                  // (z_q - z)
            st   = zz + diff;                // z + sg(z_q - z)
            lp  += diff * diff;
        }
        out[(size_t)grow * ED + lane] = st;
        if (lane == 0) idxsh[w * RPW + r] = i;
    }

    // ---- deterministic loss partial ----
#pragma unroll
    for (int m = 1; m < 64; m <<= 1) lp += __shfl_xor(lp, m);
    if (lane == 0) wsum[w] = lp;
    __syncthreads();

    // ---- uniform coalesced idx store (f32) ----
    if (tid < 32) {
        int iv = idxsh[tid] & (NE - 1);
        out[(size_t)NROWS * ED + rowbase + tid] = (float)iv;
    }
    if (tid == 0)
        partials[blockIdx.x] = (wsum[0] + wsum[1]) + (wsum[2] + wsum[3]);
}

// ---------------------------------------------------------------------------
// Finalize: deterministic tree-sum of 1024 partials -> loss scalar (f32)
// ---------------------------------------------------------------------------
__global__ void vq_finalize(const float* __restrict__ partials,
                            float* __restrict__ out)
{
    __shared__ float red[256];
    int t = threadIdx.x;
    float s = (partials[t] + partials[t + 256]) + (partials[t + 512] + partials[t + 768]);
    red[t] = s;
    __syncthreads();
    for (int m = 128; m > 0; m >>= 1) {
        if (t < m) red[t] += red[t + m];
        __syncthreads();
    }
    if (t == 0) {
        float mean = red[0] / (float)((size_t)NROWS * ED);
        out[(size_t)NROWS * ED + NROWS] = mean + 0.25f * mean;  // (1+BETA)*mean
    }
}

extern "C" void kernel_launch(void* const* d_in, const int* in_sizes, int n_in,
                              void* d_out, int out_size, void* d_ws, size_t ws_size,
                              hipStream_t stream)
{
    (void)in_sizes; (void)n_in; (void)out_size; (void)ws_size;
    const float* z  = (const float*)d_in[0];
    const float* cb = (const float*)d_in[1];
    float* out = (float*)d_out;
    float* ssq      = (float*)d_ws;          // 1024 f32
    float* partials = ssq + NE;              // 1024 f32

    vq_prep<<<4, 256, 0, stream>>>(cb, ssq);
    vq_main<<<1024, 256, 0, stream>>>(z, cb, ssq, out, partials);
    vq_finalize<<<1, 256, 0, stream>>>(partials, out);
}